// Round 3
// baseline (193.027 us; speedup 1.0000x reference)
//
#include <hip/hip_runtime.h>

// SpikingEmbedding: embed gather -> sigmoid rate -> 16-step LIF -> spikes
// B=8, S=512, D=512, T=16, VOCAB=50257, DECAY=0.9, THRESHOLD=1.0
// out[b][t][s][d] float32, values in {0,1}.
//
// R3 = R1 with compile fix: __builtin_nontemporal_store requires a native
// clang vector type, not HIP's float4 class -> use ext_vector_type(4) float.
// - output is 134 MB write-once data -> non-temporal stores (nt bit,
//   bypass L2/L3 write-allocate pollution).
// - ids[bs] is wave-uniform -> readfirstlane scalarizes the table-row base.
// Numerics identical to the 189.5 µs harness-verified kernel.

#define B_DIM 8
#define S_DIM 512
#define D_DIM 512
#define T_DIM 16

typedef float f32x4 __attribute__((ext_vector_type(4)));

__global__ __launch_bounds__(256) void
SpikingEmbedding_84155589198552_kernel(const int* __restrict__ ids,
                                       const float* __restrict__ table,
                                       float* __restrict__ out) {
    // One thread per (b, s, d4) where d4 indexes a float4 chunk of D.
    // Total threads = B*S*(D/4) = 8*512*128 = 524288.
    const int tid = blockIdx.x * blockDim.x + threadIdx.x;
    const int d4 = tid & (D_DIM / 4 - 1);   // 0..127
    const int bs = tid >> 7;                // b*S + s, 0..4095
    const int b  = bs >> 9;                 // 0..7
    const int s  = bs & (S_DIM - 1);        // 0..511

    // bs is constant across each 64-lane wave (128 consecutive threads share
    // one bs, and waves are 64-aligned within the block), so the id is
    // wave-uniform: scalarize it. Row base lands in SGPRs; the row load
    // becomes saddr-form addressing.
    const int id = __builtin_amdgcn_readfirstlane(ids[bs]);

    // Coalesced 16B row load (cached: rows may be shared / re-hit in L2/L3)
    const f32x4 e = *reinterpret_cast<const f32x4*>(
        table + (size_t)id * D_DIM + (size_t)d4 * 4);

    // sigmoid in precise f32 (no fast-math approximations) — matches ref
    const float r0 = 1.0f / (1.0f + expf(-e.x));
    const float r1 = 1.0f / (1.0f + expf(-e.y));
    const float r2 = 1.0f / (1.0f + expf(-e.z));
    const float r3 = 1.0f / (1.0f + expf(-e.w));

    float v0 = 0.0f, v1 = 0.0f, v2 = 0.0f, v3 = 0.0f;

    // out flat index: ((b*T + t)*S + s)*D + d
    float* outp = out + ((size_t)b * T_DIM * S_DIM * D_DIM)
                      + ((size_t)s * D_DIM) + ((size_t)d4 * 4);

#pragma unroll
    for (int t = 0; t < T_DIM; ++t) {
        // v = DECAY*v + r   (separate mul/add rounding to match numpy ref)
        v0 = __fadd_rn(__fmul_rn(0.9f, v0), r0);
        v1 = __fadd_rn(__fmul_rn(0.9f, v1), r1);
        v2 = __fadd_rn(__fmul_rn(0.9f, v2), r2);
        v3 = __fadd_rn(__fmul_rn(0.9f, v3), r3);

        // spike = (v - 1 >= 0); for v in [0,1.9) this equals (v >= 1)
        const float s0 = (v0 >= 1.0f) ? 1.0f : 0.0f;
        const float s1 = (v1 >= 1.0f) ? 1.0f : 0.0f;
        const float s2 = (v2 >= 1.0f) ? 1.0f : 0.0f;
        const float s3 = (v3 >= 1.0f) ? 1.0f : 0.0f;

        // soft reset: v -= spike * THRESHOLD (exact by Sterbenz for v in [0.5,2))
        v0 = __fsub_rn(v0, s0);
        v1 = __fsub_rn(v1, s1);
        v2 = __fsub_rn(v2, s2);
        v3 = __fsub_rn(v3, s3);

        f32x4 o;
        o.x = s0; o.y = s1; o.z = s2; o.w = s3;
        // Non-temporal: 134 MB write-once stream, never re-read. Bypass
        // L2/L3 write-allocate so the caches keep the embed table instead.
        __builtin_nontemporal_store(
            o, reinterpret_cast<f32x4*>(outp + (size_t)t * (S_DIM * D_DIM)));
    }
}

extern "C" void kernel_launch(void* const* d_in, const int* in_sizes, int n_in,
                              void* d_out, int out_size, void* d_ws, size_t ws_size,
                              hipStream_t stream) {
    const int*   ids   = (const int*)d_in[0];     // [8, 512] int32
    const float* table = (const float*)d_in[1];   // [50257, 512] f32
    float*       out   = (float*)d_out;           // [8, 16, 512, 512] f32

    const int total_threads = B_DIM * S_DIM * (D_DIM / 4);  // 524288
    const int block = 256;
    const int grid  = total_threads / block;                // 2048

    SpikingEmbedding_84155589198552_kernel<<<grid, block, 0, stream>>>(ids, table, out);
}

// Round 4
// 189.583 us; speedup vs baseline: 1.0182x; 1.0182x over previous
//
#include <hip/hip_runtime.h>

// SpikingEmbedding: embed gather -> sigmoid rate -> 16-step LIF -> spikes
// B=8, S=512, D=512, T=16, VOCAB=50257, DECAY=0.9, THRESHOLD=1.0
// out[b][t][s][d] float32, values in {0,1}.
//
// R4: revert nt stores (R3 measured 193.0 vs 189.5 no-nt anchor; rocprof
// shows the harness's 512 MiB poison fills at 81% peak dominate dur_us —
// kernel itself is <83 µs, near its 134 MB write roofline of ~21 µs).
// Plain float4 stores let L2 write-combine the stream like the fill does.
// Keep readfirstlane id scalarization (wave-uniform, fewer VALU).

#define B_DIM 8
#define S_DIM 512
#define D_DIM 512
#define T_DIM 16

__global__ __launch_bounds__(256) void
SpikingEmbedding_84155589198552_kernel(const int* __restrict__ ids,
                                       const float* __restrict__ table,
                                       float* __restrict__ out) {
    // One thread per (b, s, d4) where d4 indexes a float4 chunk of D.
    // Total threads = B*S*(D/4) = 8*512*128 = 524288. Grid fully resident:
    // 2048 blocks = 8 blocks/CU x 256 CUs at 4 waves each.
    const int tid = blockIdx.x * blockDim.x + threadIdx.x;
    const int d4 = tid & (D_DIM / 4 - 1);   // 0..127
    const int bs = tid >> 7;                // b*S + s, 0..4095
    const int b  = bs >> 9;                 // 0..7
    const int s  = bs & (S_DIM - 1);        // 0..511

    // bs is constant across each 64-lane wave (128 consecutive threads share
    // one bs), so the id is wave-uniform: scalarize it. Row base lands in
    // SGPRs; the row load becomes saddr-form addressing.
    const int id = __builtin_amdgcn_readfirstlane(ids[bs]);

    // Coalesced 16B row load (1 KB per wave, contiguous within the row)
    const float4 e = *reinterpret_cast<const float4*>(
        table + (size_t)id * D_DIM + (size_t)d4 * 4);

    // sigmoid in precise f32 (no fast-math approximations) — matches ref
    const float r0 = 1.0f / (1.0f + expf(-e.x));
    const float r1 = 1.0f / (1.0f + expf(-e.y));
    const float r2 = 1.0f / (1.0f + expf(-e.z));
    const float r3 = 1.0f / (1.0f + expf(-e.w));

    float v0 = 0.0f, v1 = 0.0f, v2 = 0.0f, v3 = 0.0f;

    // out flat index: ((b*T + t)*S + s)*D + d
    float* outp = out + ((size_t)b * T_DIM * S_DIM * D_DIM)
                      + ((size_t)s * D_DIM) + ((size_t)d4 * 4);

#pragma unroll
    for (int t = 0; t < T_DIM; ++t) {
        // v = DECAY*v + r   (separate mul/add rounding to match numpy ref)
        v0 = __fadd_rn(__fmul_rn(0.9f, v0), r0);
        v1 = __fadd_rn(__fmul_rn(0.9f, v1), r1);
        v2 = __fadd_rn(__fmul_rn(0.9f, v2), r2);
        v3 = __fadd_rn(__fmul_rn(0.9f, v3), r3);

        // spike = (v - 1 >= 0); v < 1.9 always, so this equals (v >= 1)
        const float s0 = (v0 >= 1.0f) ? 1.0f : 0.0f;
        const float s1 = (v1 >= 1.0f) ? 1.0f : 0.0f;
        const float s2 = (v2 >= 1.0f) ? 1.0f : 0.0f;
        const float s3 = (v3 >= 1.0f) ? 1.0f : 0.0f;

        // soft reset: v -= spike * THRESHOLD (exact by Sterbenz for v in [1,1.9))
        v0 = __fsub_rn(v0, s0);
        v1 = __fsub_rn(v1, s1);
        v2 = __fsub_rn(v2, s2);
        v3 = __fsub_rn(v3, s3);

        float4 o;
        o.x = s0; o.y = s1; o.z = s2; o.w = s3;
        // Plain store: 1 KB/wave contiguous per instruction; L2 write-combines
        // full lines (same path as the 81%-of-peak fill kernel).
        *reinterpret_cast<float4*>(outp + (size_t)t * (S_DIM * D_DIM)) = o;
    }
}

extern "C" void kernel_launch(void* const* d_in, const int* in_sizes, int n_in,
                              void* d_out, int out_size, void* d_ws, size_t ws_size,
                              hipStream_t stream) {
    const int*   ids   = (const int*)d_in[0];     // [8, 512] int32
    const float* table = (const float*)d_in[1];   // [50257, 512] f32
    float*       out   = (float*)d_out;           // [8, 16, 512, 512] f32

    const int total_threads = B_DIM * S_DIM * (D_DIM / 4);  // 524288
    const int block = 256;
    const int grid  = total_threads / block;                // 2048

    SpikingEmbedding_84155589198552_kernel<<<grid, block, 0, stream>>>(ids, table, out);
}